// Round 1
// baseline (1560.990 us; speedup 1.0000x reference)
//
#include <hip/hip_runtime.h>

// ---------- types ----------
typedef __attribute__((ext_vector_type(8))) short bf16x8;   // 8 bf16 in 4 VGPRs
typedef __attribute__((ext_vector_type(4))) float f32x4;

// ---------- helpers ----------
__device__ __forceinline__ unsigned short f2bf(float f) {
    unsigned int u = __float_as_uint(f);
    u += 0x7fffu + ((u >> 16) & 1u);      // RNE
    return (unsigned short)(u >> 16);
}

__device__ __forceinline__ void async16(const void* g, void* l) {
    // global -> LDS direct, 16B per lane; LDS dest = wave-uniform base + lane*16
    __builtin_amdgcn_global_load_lds(
        (__attribute__((address_space(1))) void*)const_cast<void*>(g),
        (__attribute__((address_space(3))) void*)l, 16, 0, 0);
}

// ---------- kernel: fp32 -> bf16 elementwise (hidden states) ----------
__global__ __launch_bounds__(256) void cvt_f32_bf16(const float* __restrict__ in,
                                                    unsigned short* __restrict__ out,
                                                    long n4) {
    long i = ((long)blockIdx.x * 256 + threadIdx.x);
    if (i >= n4) return;
    const float4 v = *(const float4*)(in + i * 4);
    ushort4 r;
    r.x = f2bf(v.x); r.y = f2bf(v.y); r.z = f2bf(v.z); r.w = f2bf(v.w);
    *(ushort4*)(out + i * 4) = r;
}

// ---------- kernel: transpose + convert  fp32 [K][N] -> bf16 [N][K] ----------
__global__ __launch_bounds__(256) void transpose_cvt(const float* __restrict__ in,
                                                     unsigned short* __restrict__ out,
                                                     const int K, const int N) {
    __shared__ unsigned short tile[64][65];
    const float* src = in + (size_t)blockIdx.z * K * N;
    unsigned short* dst = out + (size_t)blockIdx.z * K * N;
    const int n0 = blockIdx.x * 64;
    const int k0 = blockIdx.y * 64;
    const int t = threadIdx.x;
#pragma unroll
    for (int i = 0; i < 4; ++i) {
        int slot = t + i * 256;           // 0..1023
        int r  = slot >> 4;               // k-local 0..63
        int cq = (slot & 15) * 4;         // n-local quad
        const float4 v = *(const float4*)(src + (size_t)(k0 + r) * N + n0 + cq);
        tile[r][cq + 0] = f2bf(v.x);
        tile[r][cq + 1] = f2bf(v.y);
        tile[r][cq + 2] = f2bf(v.z);
        tile[r][cq + 3] = f2bf(v.w);
    }
    __syncthreads();
#pragma unroll
    for (int i = 0; i < 4; ++i) {
        int slot = t + i * 256;
        int nr = slot >> 4;               // n-local 0..63
        int kq = (slot & 15) * 4;         // k-local quad
        ushort4 w;
        w.x = tile[kq + 0][nr];
        w.y = tile[kq + 1][nr];
        w.z = tile[kq + 2][nr];
        w.w = tile[kq + 3][nr];
        *(ushort4*)(dst + (size_t)(n0 + nr) * K + k0 + kq) = w;
    }
}

// ---------- kernel: bf16 MFMA GEMM, A[M][K] x BT[N][K] ----------
// BM=128, BN=64, BK=32, 256 threads = 4 waves (2x2), wave tile 64x32.
// 3-buffer LDS pipeline, counted vmcnt (never 0 in steady state), raw s_barrier.
// DUAL: gate rows at (bn0+n), up rows at (bn0+n+up_off); epilogue = up*silu(gate) -> bf16
// !DUAL: plain GEMM, fp32 out.
template <bool DUAL>
__global__ __launch_bounds__(256, 2) void gemm_bt(const unsigned short* __restrict__ A,
                                                  const unsigned short* __restrict__ BT,
                                                  void* __restrict__ Cv,
                                                  const int M, const int N, const int K,
                                                  const long sAe, const long sBe, const long sCe,
                                                  const int up_off) {
    constexpr int ASZ = 128 * 32;                      // u16 elems per A tile (8 KiB)
    constexpr int BSZ = (DUAL ? 2 : 1) * 64 * 32;      // u16 elems per B tile
    __shared__ unsigned short As[3 * ASZ];
    __shared__ unsigned short Bs[3 * BSZ];

    const int e = blockIdx.z;
    const unsigned short* Ae = A + (long)e * sAe;
    const unsigned short* Be = BT + (long)e * sBe;

    // T1: XCD-bijective swizzle of the per-expert 2D grid (valid when nwg%8==0)
    const unsigned gx = gridDim.x;
    const unsigned nwg = gx * gridDim.y;
    const unsigned lid = blockIdx.y * gx + blockIdx.x;
    const unsigned swz = (nwg & 7u) ? lid : ((lid & 7u) * (nwg >> 3) + (lid >> 3));
    const int bn0 = (int)(swz % gx) * 64;
    const int bm0 = (int)(swz / gx) * 128;

    const int tid  = threadIdx.x;
    const int wave = tid >> 6;
    const int lane = tid & 63;
    const int wm = wave >> 1;         // wave row: 0/1 -> rows wm*64
    const int wn = wave & 1;          // wave col: 0/1 -> cols wn*32
    const int l4 = lane >> 2;         // staging: row within 16-row group
    const int lk = (lane & 3) * 8;    // staging: k offset (8 bf16 = 16B)
    const int fm = lane & 15;         // fragment m/n index
    const int fq = lane >> 4;         // fragment quad (k octet)

    constexpr int NH = DUAL ? 2 : 1;
    f32x4 acc[NH][4][2];
    const f32x4 zero = {0.f, 0.f, 0.f, 0.f};
#pragma unroll
    for (int h = 0; h < NH; ++h)
#pragma unroll
        for (int i = 0; i < 4; ++i)
#pragma unroll
            for (int j = 0; j < 2; ++j) acc[h][i][j] = zero;

    const int nt = K >> 5;            // number of 32-wide K tiles (>= 3 here)

    // per-wave loads per tile: DUAL = 4 (2 A + 2 B), plain = 3 (2 A + 1 B)
    auto stage = [&](int t, int buf) {
        unsigned short* as = As + buf * ASZ;
        unsigned short* bs = Bs + buf * BSZ;
        const int k0 = t << 5;
#pragma unroll
        for (int s = 0; s < 2; ++s) {
            const int r = wave * 32 + s * 16;
            async16(Ae + (long)(bm0 + r + l4) * K + k0 + lk, (void*)(as + r * 32));
        }
        if (DUAL) {
            const int h = wave >> 1;          // waves 0,1 -> gate; 2,3 -> up
#pragma unroll
            for (int s = 0; s < 2; ++s) {
                const int r = (wave & 1) * 32 + s * 16;
                async16(Be + (long)(bn0 + h * up_off + r + l4) * K + k0 + lk,
                        (void*)(bs + h * 2048 + r * 32));
            }
        } else {
            const int r = wave * 16;
            async16(Be + (long)(bn0 + r + l4) * K + k0 + lk, (void*)(bs + r * 32));
        }
    };

    auto compute = [&](int buf) {
        const unsigned short* as = As + buf * ASZ;
        const unsigned short* bs = Bs + buf * BSZ;
        bf16x8 af[4];
#pragma unroll
        for (int i = 0; i < 4; ++i)
            af[i] = *(const bf16x8*)(as + (wm * 64 + i * 16 + fm) * 32 + fq * 8);
#pragma unroll
        for (int h = 0; h < NH; ++h) {
            bf16x8 bfr[2];
#pragma unroll
            for (int j = 0; j < 2; ++j)
                bfr[j] = *(const bf16x8*)(bs + h * 2048 + (wn * 32 + j * 16 + fm) * 32 + fq * 8);
#pragma unroll
            for (int i = 0; i < 4; ++i)
#pragma unroll
                for (int j = 0; j < 2; ++j)
                    acc[h][i][j] = __builtin_amdgcn_mfma_f32_16x16x32_bf16(af[i], bfr[j],
                                                                           acc[h][i][j], 0, 0, 0);
        }
    };

    // ---- prologue: 2-deep prefetch ----
    stage(0, 0);
    stage(1, 1);

    int buf = 0;
    for (int t = 0; t < nt; ++t) {
        const int ahead = nt - 1 - t;             // uniform across block
        if (ahead >= 2) {
            int nb = buf + 2; if (nb >= 3) nb -= 3;
            stage(t + 2, nb);
            // wait for tile t: tiles t+1,t+2 stay in flight
            if (DUAL) asm volatile("s_waitcnt vmcnt(8)" ::: "memory");
            else      asm volatile("s_waitcnt vmcnt(6)" ::: "memory");
        } else if (ahead == 1) {
            if (DUAL) asm volatile("s_waitcnt vmcnt(4)" ::: "memory");
            else      asm volatile("s_waitcnt vmcnt(3)" ::: "memory");
        } else {
            asm volatile("s_waitcnt vmcnt(0)" ::: "memory");
        }
        __builtin_amdgcn_s_barrier();             // tile t visible to all waves
        compute(buf);
        if (t + 1 < nt) {
            asm volatile("" ::: "memory");        // keep ds_reads above the barrier
            __builtin_amdgcn_s_barrier();         // all reads of buf done before reuse
        }
        buf = (buf == 2) ? 0 : buf + 1;
    }

    // ---- epilogue; C/D layout: col = lane&15, row = (lane>>4)*4 + reg ----
    if (DUAL) {
        unsigned short* C = (unsigned short*)Cv + (long)e * sCe;
#pragma unroll
        for (int i = 0; i < 4; ++i)
#pragma unroll
            for (int j = 0; j < 2; ++j)
#pragma unroll
                for (int r = 0; r < 4; ++r) {
                    const int row = bm0 + wm * 64 + i * 16 + fq * 4 + r;
                    const int col = bn0 + wn * 32 + j * 16 + fm;
                    const float g = acc[0][i][j][r];
                    const float u = acc[1][i][j][r];
                    const float s = g / (1.f + __expf(-g));   // silu
                    C[(long)row * N + col] = f2bf(u * s);
                }
    } else {
        float* C = (float*)Cv + (long)e * sCe;
#pragma unroll
        for (int i = 0; i < 4; ++i)
#pragma unroll
            for (int j = 0; j < 2; ++j)
#pragma unroll
                for (int r = 0; r < 4; ++r) {
                    const int row = bm0 + wm * 64 + i * 16 + fq * 4 + r;
                    const int col = bn0 + wn * 32 + j * 16 + fm;
                    C[(long)row * N + col] = acc[0][i][j][r];
                }
    }
}

// ---------- host ----------
extern "C" void kernel_launch(void* const* d_in, const int* in_sizes, int n_in,
                              void* d_out, int out_size, void* d_ws, size_t ws_size,
                              hipStream_t stream) {
    const float* hs = (const float*)d_in[0];   // [8192][2048]
    const float* w1 = (const float*)d_in[1];   // [8][2048][8192]
    const float* w2 = (const float*)d_in[2];   // [8][4096][2048]
    float* out = (float*)d_out;                // [8192][2048]

    unsigned short* ws_h = (unsigned short*)d_ws;           // hidden bf16: 8192*2048
    unsigned short* ws_g = ws_h + (size_t)8192 * 2048;      // gated bf16:  8192*4096
    unsigned short* ws_w = ws_g + (size_t)8192 * 4096;      // weight-T chunk

    const size_t fixed = ((size_t)8192 * 2048 + (size_t)8192 * 4096) * 2;
    const size_t avail = ws_size > fixed ? ws_size - fixed : 0;
    const size_t w1b = (size_t)8192 * 2048 * 2;   // per-expert W1T bytes
    const size_t w2b = (size_t)2048 * 4096 * 2;   // per-expert W2T bytes
    int c1 = (int)(avail / w1b); if (c1 < 1) c1 = 1; if (c1 > 8) c1 = 8;
    int c2 = (int)(avail / w2b); if (c2 < 1) c2 = 1; if (c2 > 8) c2 = 8;

    // hidden -> bf16
    {
        const long n4 = (long)8192 * 2048 / 4;
        cvt_f32_bf16<<<dim3((unsigned)((n4 + 255) / 256)), dim3(256), 0, stream>>>(hs, ws_h, n4);
    }

    // layer 1: transpose W1 chunk, grouped GEMM + SwiGLU -> gated bf16
    for (int e0 = 0; e0 < 8; e0 += c1) {
        const int ne = (8 - e0 < c1) ? (8 - e0) : c1;
        transpose_cvt<<<dim3(8192 / 64, 2048 / 64, ne), 256, 0, stream>>>(
            w1 + (size_t)e0 * 2048 * 8192, ws_w, 2048, 8192);
        gemm_bt<true><<<dim3(4096 / 64, 1024 / 128, ne), 256, 0, stream>>>(
            ws_h + (size_t)e0 * 1024 * 2048, ws_w, (void*)(ws_g + (size_t)e0 * 1024 * 4096),
            1024, 4096, 2048, 1024L * 2048, 8192L * 2048, 1024L * 4096, 4096);
    }

    // layer 2: transpose W2 chunk, grouped GEMM -> fp32 out
    for (int e0 = 0; e0 < 8; e0 += c2) {
        const int ne = (8 - e0 < c2) ? (8 - e0) : c2;
        transpose_cvt<<<dim3(2048 / 64, 4096 / 64, ne), 256, 0, stream>>>(
            w2 + (size_t)e0 * 4096 * 2048, ws_w, 4096, 2048);
        gemm_bt<false><<<dim3(2048 / 64, 1024 / 128, ne), 256, 0, stream>>>(
            ws_g + (size_t)e0 * 1024 * 4096, ws_w, (void*)(out + (size_t)e0 * 1024 * 2048),
            1024, 2048, 4096, 1024L * 4096, 2048L * 4096, 1024L * 2048, 0);
    }
}